// Round 1
// baseline (193.626 us; speedup 1.0000x reference)
//
#include <hip/hip_runtime.h>
#include <math.h>

#define GAMMA 0.3f
#define EPS 1e-6f
#define B_SZ 16
#define NH 32
#define KF 32768
#define KI 16384
#define KHEADS 7   // ceil(0.2 * 32)

// ---- workspace layout (float indices) ----
constexpr int OFF_RAWS = 0;      // 512  raw masked softmax denom per (b,h)
constexpr int OFF_RAWP = 512;    // 512  raw pos numerator
constexpr int OFF_RAWN = 1024;   // 512  raw neg numerator
constexpr int IOFF_ARR = 1536;   // 16 arrive counters (int), stride 32 ints (cacheline-padded)
constexpr int OFF_RFF  = 4096;   // B*KF  rf expanded: rf>=0 on-mask, -1 off-mask

// NOTE (R6 lesson): do NOT fuse via hipLaunchCooperativeKernel/grid.sync() —
// measured ~120 µs barrier cost on gfx950 (k_fused 151 µs vs ~32 µs of work).
// This version instead uses 2 plain dispatches + a hand-rolled per-batch
// arrive-barrier in k_main (64 blocks/batch; all 1024 blocks co-resident by
// __launch_bounds__(256,4) -> 4 blocks/CU x 256 CU = 1024).

// ---- k_pre: 256 blocks, blk = b*16 + c (c = 2048-position chunk of the attn row).
//      Fuses: per-(b,feat) stats (redundant per 16 blocks, L2-resident reads),
//      mask prefix count, rf compute, expand-to-full-K. Block 0 zeroes accums. ----
__global__ __launch_bounds__(256) void k_pre(const float* __restrict__ fC,
        const float* __restrict__ fA, const float* __restrict__ fD,
        const float* __restrict__ fB, const int* __restrict__ mask,
        float* __restrict__ ws) {
    __shared__ double r1[256], r2[256];
    __shared__ float s_mu[4], s_sd[4];
    __shared__ int sc[256];
    __shared__ float rfbuf[2048];
    int blk = blockIdx.x, t = threadIdx.x;
    int b = blk >> 4, c = blk & 15;

    if (blk == 0) {
        for (int i = t; i < 1536; i += 256) ws[OFF_RAWS + i] = 0.f;
        if (t < 16) ((int*)ws)[IOFF_ARR + t * 32] = 0;
    }

    // per-feat mean/(std+eps) for batch b (each of the 16 chunk-blocks of b
    // recomputes; feats are 4 MB total so 15/16 of these reads hit L2/LLC)
    const float* feats[4] = {fC, fA, fD, fB};
    #pragma unroll 1
    for (int f = 0; f < 4; ++f) {
        const float* src = feats[f] + (size_t)b * KI;
        double s = 0.0, s2 = 0.0;
        for (int i = t; i < KI / 4; i += 256) {
            float4 v = ((const float4*)src)[i];
            s  += (double)v.x + (double)v.y + (double)v.z + (double)v.w;
            s2 += (double)v.x * v.x + (double)v.y * v.y + (double)v.z * v.z + (double)v.w * v.w;
        }
        r1[t] = s; r2[t] = s2; __syncthreads();
        for (int off = 128; off > 0; off >>= 1) {
            if (t < off) { r1[t] += r1[t + off]; r2[t] += r2[t + off]; }
            __syncthreads();
        }
        if (t == 0) {
            double mu  = r1[0] * (1.0 / KI);
            double var = fmax(r2[0] * (1.0 / KI) - mu * mu, 0.0);
            s_mu[f] = (float)mu;
            s_sd[f] = (float)(sqrt(var) + (double)EPS);
        }
        __syncthreads();
    }

    // prefix: number of image tokens in chunks [0, c) of this row (L2-hot)
    const int* mrowb = mask + (size_t)b * KF;
    int pre = 0;
    for (int i = t; i < c * 512; i += 256) {
        int4 m = ((const int4*)mrowb)[i];
        pre += (m.x != 0) + (m.y != 0) + (m.z != 0) + (m.w != 0);
    }
    sc[t] = pre; __syncthreads();
    for (int off = 128; off > 0; off >>= 1) {
        if (t < off) sc[t] += sc[t + off];
        __syncthreads();
    }
    int boff = sc[0];
    __syncthreads();

    // own-chunk mask + in-block scan for local ranks
    const int* mrow = mrowb + c * 2048;
    int4 m0 = *(const int4*)(mrow + t * 8);
    int4 m1 = *(const int4*)(mrow + t * 8 + 4);
    int mv[8] = {m0.x, m0.y, m0.z, m0.w, m1.x, m1.y, m1.z, m1.w};
    int cnt = 0;
    #pragma unroll
    for (int j = 0; j < 8; ++j) cnt += (mv[j] != 0);
    sc[t] = cnt; __syncthreads();
    for (int off = 1; off < 256; off <<= 1) {
        int v = (t >= off) ? sc[t - off] : 0;
        __syncthreads();
        sc[t] += v;
        __syncthreads();
    }
    int total = sc[255];
    int rloc = sc[t] - cnt;                      // local rank of my first element

    // rf for the contiguous image-token range [boff, boff+total)
    float mu0 = s_mu[0], sd0 = s_sd[0], mu1 = s_mu[1], sd1 = s_sd[1];
    float mu2 = s_mu[2], sd2 = s_sd[2], mu3 = s_mu[3], sd3 = s_sd[3];
    for (int j = t; j < total; j += 256) {
        size_t idx = (size_t)b * KI + boff + j;
        float Ct = fmaxf((fC[idx] - mu0) / sd0, 0.f);
        float At = 1.f / (1.f + __expf(-((fA[idx] - mu1) / sd1)));
        float Dt = 1.f / (1.f + __expf(-((fD[idx] - mu2) / sd2)));
        float Bt = 1.f / (1.f + __expf(-((fB[idx] - mu3) / sd3)));
        float denom = fmaxf(1.f + 0.5f * (Dt + Bt), EPS);
        rfbuf[j] = fmaxf(Ct * At / denom, 0.f);
    }
    __syncthreads();
    float vr[8];
    #pragma unroll
    for (int j = 0; j < 8; ++j) {
        if (mv[j]) { vr[j] = rfbuf[rloc]; ++rloc; }
        else       { vr[j] = -1.f; }
    }
    float* rff = ws + OFF_RFF + (size_t)blk * 2048 + t * 8;
    *(float4*)(rff)     = *(float4*)(vr);
    *(float4*)(rff + 4) = *(float4*)(vr + 4);
}

// ---- k_main: 1024 blocks, g = bh*2 + half. Phase A: read attn half-row into
//      registers (16 x float4/thread), accumulate raw S/P/N, atomicAdd.
//      Per-batch arrive barrier (64 blocks). Phase B: top-k roles, write
//      out = attn(reg) + gp*rf - gn*low_rf. attn is read from HBM exactly once. ----
__global__ __launch_bounds__(256, 4) void k_main(const float* __restrict__ attn,
        float* __restrict__ ws, float* __restrict__ out) {
    int g = blockIdx.x, t = threadIdx.x;
    int bh = g >> 1, half = g & 1;
    int b = bh >> 5, h = bh & 31;
    const float* xr  = attn + ((size_t)bh << 15) + ((size_t)half << 14);
    const float* rff = ws + OFF_RFF + ((size_t)b << 15) + ((size_t)half << 14);

    float4 r[16];
    float S = 0.f, P = 0.f, N = 0.f;
    #pragma unroll
    for (int i = 0; i < 16; ++i) {
        int k = (i * 256 + t) * 4;
        float4 xs = *(const float4*)(xr + k);
        float4 rv = *(const float4*)(rff + k);
        r[i] = xs;
        float xa[4] = {xs.x, xs.y, xs.z, xs.w};
        float va[4] = {rv.x, rv.y, rv.z, rv.w};
        #pragma unroll
        for (int j = 0; j < 4; ++j) {
            float e = __expf(xa[j]);            // |x|<~6 -> no overflow, no max-sub
            bool on = va[j] >= 0.f;
            float rfv  = fmaxf(va[j], 0.f);
            float lrfv = on ? fmaxf(1.f - va[j], 0.f) : 0.f;
            S += on ? e : 0.f;
            P = fmaf(e, rfv, P);
            N = fmaf(e, lrfv, N);
        }
    }
    __shared__ float rs[256], rp[256], rn[256];
    rs[t] = S; rp[t] = P; rn[t] = N;
    __syncthreads();
    for (int off = 128; off > 0; off >>= 1) {
        if (t < off) { rs[t] += rs[t + off]; rp[t] += rp[t + off]; rn[t] += rn[t + off]; }
        __syncthreads();
    }

    // per-batch arrive barrier: 64 blocks of batch b (all co-resident by
    // __launch_bounds__(256,4): grid 1024 == 4 blocks/CU x 256 CU)
    int* arr = (int*)ws + IOFF_ARR + b * 32;
    if (t == 0) {
        atomicAdd(&ws[OFF_RAWS + bh], rs[0]);
        atomicAdd(&ws[OFF_RAWP + bh], rp[0]);
        atomicAdd(&ws[OFF_RAWN + bh], rn[0]);
        __threadfence();                        // release: sums visible before arrive
        atomicAdd(arr, 1);
        while (__hip_atomic_load(arr, __ATOMIC_RELAXED, __HIP_MEMORY_SCOPE_AGENT) < 64)
            __builtin_amdgcn_s_sleep(2);
    }
    __syncthreads();

    // Phase B: head roles (jax top_k semantics: value desc, tie -> lower index,
    // strictly-positive only). AGENT-scope loads read the L2 coherence point.
    __shared__ float ssp[NH], snv[NH];
    __shared__ int smp[NH];
    __shared__ float s_gp, s_gn;
    if (t < NH) {
        float S0 = __hip_atomic_load(&ws[OFF_RAWS + b * NH + t], __ATOMIC_RELAXED, __HIP_MEMORY_SCOPE_AGENT);
        float Pp = __hip_atomic_load(&ws[OFF_RAWP + b * NH + t], __ATOMIC_RELAXED, __HIP_MEMORY_SCOPE_AGENT);
        float Nn = __hip_atomic_load(&ws[OFF_RAWN + b * NH + t], __ATOMIC_RELAXED, __HIP_MEMORY_SCOPE_AGENT);
        ssp[t] = Pp / S0;
        snv[t] = Nn / S0;
    }
    __syncthreads();
    if (t < NH) {
        float sp = ssp[t];
        int c2 = 0;
        for (int j = 0; j < NH; ++j) { float o = ssp[j]; c2 += (o > sp) || (o == sp && j < t); }
        smp[t] = (c2 < KHEADS) && (sp > 0.f);
    }
    __syncthreads();
    if (t < NH && smp[t]) snv[t] = -INFINITY;
    __syncthreads();
    if (t == 0) {
        float gp = 0.f, gn = 0.f;
        if (smp[h]) gp = GAMMA;
        else {
            float nv = snv[h];
            int c2 = 0;
            for (int j = 0; j < NH; ++j) { float o = snv[j]; c2 += (o > nv) || (o == nv && j < h); }
            if ((c2 < KHEADS) && (nv > 0.f)) gn = GAMMA;
        }
        s_gp = gp; s_gn = gn;
    }
    __syncthreads();

    float gp = s_gp, gn = s_gn;
    float* op = out + ((size_t)bh << 15) + ((size_t)half << 14);
    #pragma unroll
    for (int i = 0; i < 16; ++i) {
        int k = (i * 256 + t) * 4;
        float4 rv = *(const float4*)(rff + k);   // L2-hot (read in phase A)
        float va[4] = {rv.x, rv.y, rv.z, rv.w};
        float xa[4] = {r[i].x, r[i].y, r[i].z, r[i].w};
        float oa[4];
        #pragma unroll
        for (int j = 0; j < 4; ++j) {
            bool on = va[j] >= 0.f;
            float rfv  = fmaxf(va[j], 0.f);
            float lrfv = on ? fmaxf(1.f - va[j], 0.f) : 0.f;
            oa[j] = xa[j] + gp * rfv - gn * lrfv;
        }
        float4 o = {oa[0], oa[1], oa[2], oa[3]};
        *(float4*)(op + k) = o;
    }
}

extern "C" void kernel_launch(void* const* d_in, const int* in_sizes, int n_in,
                              void* d_out, int out_size, void* d_ws, size_t ws_size,
                              hipStream_t stream) {
    const float* attn = (const float*)d_in[0];   // f32 [B,H,KF]
    const int*   mask = (const int*)d_in[1];     // int32 [B,KF]
    const float* fC   = (const float*)d_in[2];   // f32 [B,KI]
    const float* fA   = (const float*)d_in[3];
    const float* fD   = (const float*)d_in[4];
    const float* fB   = (const float*)d_in[5];
    float* out = (float*)d_out;                  // f32 [B,H,KF]
    float* ws = (float*)d_ws;

    k_pre <<<256, 256, 0, stream>>>(fC, fA, fD, fB, mask, ws);
    k_main<<<1024, 256, 0, stream>>>(attn, ws, out);
}

// Round 2
// 168.968 us; speedup vs baseline: 1.1459x; 1.1459x over previous
//
#include <hip/hip_runtime.h>
#include <math.h>

#define GAMMA 0.3f
#define EPS 1e-6f
#define B_SZ 16
#define NH 32
#define KF 32768
#define KI 16384
#define KHEADS 7   // ceil(0.2 * 32)

// ---- workspace layout (float indices) ----
constexpr int OFF_RAWS = 0;      // 512  raw masked softmax denom per (b,h)
constexpr int OFF_RAWP = 512;    // 512  raw pos numerator
constexpr int OFF_RAWN = 1024;   // 512  raw neg numerator
constexpr int OFF_RFF  = 4096;   // B*KF  rf expanded: rf>=0 on-mask, -1 off-mask

// LESSONS (journal):
//  R6(prev session): cooperative grid.sync() fusion = ~120 µs barrier cost. NO.
//  R1(this session): hand-rolled per-batch arrive barrier + register-resident
//    attn ALSO regressed (k_main 55.5 µs @ 2 TB/s): __launch_bounds__(256,4)
//    capped VGPRs at 64 -> compiler re-loaded attn in phase B (premise dead),
//    and the barrier serialized phase A tail -> phase B storm. NO intra-kernel
//    global sync on this op.
//  Fixed timed-region overhead ~117 µs (R0: 150-33, R1: 194-75) regardless of
//    kernel structure -> minimize summed kernel time + launch count only.
//  k_out's second attn read is LLC-warm (64 MB attn << 256 MB L3, read by
//    k_scores immediately before) -> separate k_scores/k_out is near-free.

// ---- k_pre: 256 blocks, blk = b*16 + c (c = 2048-position chunk of the row).
//      Fuses: per-(b,feat) stats (recomputed per chunk-block; feats total 4 MB
//      so 15/16 of those reads are L2/LLC hits), mask prefix count, rf compute,
//      expand-to-full-K. Block 0 zeroes the raw accumulators. ----
__global__ __launch_bounds__(256) void k_pre(const float* __restrict__ fC,
        const float* __restrict__ fA, const float* __restrict__ fD,
        const float* __restrict__ fB, const int* __restrict__ mask,
        float* __restrict__ ws) {
    __shared__ double r1[256], r2[256];
    __shared__ float s_mu[4], s_sd[4];
    __shared__ int sc[256];
    __shared__ float rfbuf[2048];
    int blk = blockIdx.x, t = threadIdx.x;
    int b = blk >> 4, c = blk & 15;

    if (blk == 0 && t < 64) {
        #pragma unroll
        for (int i = 0; i < 24; ++i) ws[OFF_RAWS + i * 64 + t] = 0.f;
    }

    // per-feat mean/(std+eps) for batch b
    const float* feats[4] = {fC, fA, fD, fB};
    #pragma unroll 1
    for (int f = 0; f < 4; ++f) {
        const float* src = feats[f] + (size_t)b * KI;
        double s = 0.0, s2 = 0.0;
        for (int i = t; i < KI / 4; i += 256) {
            float4 v = ((const float4*)src)[i];
            s  += (double)v.x + (double)v.y + (double)v.z + (double)v.w;
            s2 += (double)v.x * v.x + (double)v.y * v.y + (double)v.z * v.z + (double)v.w * v.w;
        }
        r1[t] = s; r2[t] = s2; __syncthreads();
        for (int off = 128; off > 0; off >>= 1) {
            if (t < off) { r1[t] += r1[t + off]; r2[t] += r2[t + off]; }
            __syncthreads();
        }
        if (t == 0) {
            double mu  = r1[0] * (1.0 / KI);
            double var = fmax(r2[0] * (1.0 / KI) - mu * mu, 0.0);
            s_mu[f] = (float)mu;
            s_sd[f] = (float)(sqrt(var) + (double)EPS);
        }
        __syncthreads();
    }

    // prefix: number of image tokens in chunks [0, c) of this row (L2-hot)
    const int* mrowb = mask + (size_t)b * KF;
    int pre = 0;
    for (int i = t; i < c * 512; i += 256) {
        int4 m = ((const int4*)mrowb)[i];
        pre += (m.x != 0) + (m.y != 0) + (m.z != 0) + (m.w != 0);
    }
    sc[t] = pre; __syncthreads();
    for (int off = 128; off > 0; off >>= 1) {
        if (t < off) sc[t] += sc[t + off];
        __syncthreads();
    }
    int boff = sc[0];
    __syncthreads();

    // own-chunk mask + in-block scan for local ranks
    const int* mrow = mrowb + c * 2048;
    int4 m0 = *(const int4*)(mrow + t * 8);
    int4 m1 = *(const int4*)(mrow + t * 8 + 4);
    int mv[8] = {m0.x, m0.y, m0.z, m0.w, m1.x, m1.y, m1.z, m1.w};
    int cnt = 0;
    #pragma unroll
    for (int j = 0; j < 8; ++j) cnt += (mv[j] != 0);
    sc[t] = cnt; __syncthreads();
    for (int off = 1; off < 256; off <<= 1) {
        int v = (t >= off) ? sc[t - off] : 0;
        __syncthreads();
        sc[t] += v;
        __syncthreads();
    }
    int total = sc[255];
    int rloc = sc[t] - cnt;                      // local rank of my first element

    // rf for the contiguous image-token range [boff, boff+total)
    float mu0 = s_mu[0], sd0 = s_sd[0], mu1 = s_mu[1], sd1 = s_sd[1];
    float mu2 = s_mu[2], sd2 = s_sd[2], mu3 = s_mu[3], sd3 = s_sd[3];
    for (int j = t; j < total; j += 256) {
        size_t idx = (size_t)b * KI + boff + j;
        float Ct = fmaxf((fC[idx] - mu0) / sd0, 0.f);
        float At = 1.f / (1.f + __expf(-((fA[idx] - mu1) / sd1)));
        float Dt = 1.f / (1.f + __expf(-((fD[idx] - mu2) / sd2)));
        float Bt = 1.f / (1.f + __expf(-((fB[idx] - mu3) / sd3)));
        float denom = fmaxf(1.f + 0.5f * (Dt + Bt), EPS);
        rfbuf[j] = fmaxf(Ct * At / denom, 0.f);
    }
    __syncthreads();
    float vr[8];
    #pragma unroll
    for (int j = 0; j < 8; ++j) {
        if (mv[j]) { vr[j] = rfbuf[rloc]; ++rloc; }
        else       { vr[j] = -1.f; }
    }
    float* rff = ws + OFF_RFF + (size_t)blk * 2048 + t * 8;
    *(float4*)(rff)     = *(float4*)(vr);
    *(float4*)(rff + 4) = *(float4*)(vr + 4);
}

// ---- per-(b,h)-half raw masked-softmax accumulation (branchless, no max-sub:
//      |x|<~6 so e^x <= ~300, no overflow; raw sums combined via atomicAdd) ----
__global__ __launch_bounds__(256) void k_scores(const float* __restrict__ attn,
                                                float* __restrict__ ws) {
    int g = blockIdx.x, t = threadIdx.x;         // 1024 blocks: bh = g>>1, half = g&1
    int bh = g >> 1, half = g & 1;
    int b = bh >> 5;
    const float* xr  = attn + ((size_t)bh << 15) + ((size_t)half << 14);
    const float* rff = ws + OFF_RFF + ((size_t)b << 15) + ((size_t)half << 14);
    float S = 0.f, P = 0.f, N = 0.f;
    #pragma unroll 4
    for (int i = 0; i < 16; ++i) {
        int k = (i * 256 + t) * 4;
        float4 xs = *(const float4*)(xr + k);
        float4 rv = *(const float4*)(rff + k);
        float xa[4] = {xs.x, xs.y, xs.z, xs.w};
        float va[4] = {rv.x, rv.y, rv.z, rv.w};
        #pragma unroll
        for (int j = 0; j < 4; ++j) {
            float e = __expf(xa[j]);
            bool on = va[j] >= 0.f;
            float rfv  = fmaxf(va[j], 0.f);
            float lrfv = on ? fmaxf(1.f - va[j], 0.f) : 0.f;
            S += on ? e : 0.f;
            P = fmaf(e, rfv, P);
            N = fmaf(e, lrfv, N);
        }
    }
    __shared__ float rs[256], rp[256], rn[256];
    rs[t] = S; rp[t] = P; rn[t] = N;
    __syncthreads();
    for (int off = 128; off > 0; off >>= 1) {
        if (t < off) { rs[t] += rs[t + off]; rp[t] += rp[t + off]; rn[t] += rn[t + off]; }
        __syncthreads();
    }
    if (t == 0) {
        atomicAdd(&ws[OFF_RAWS + bh], rs[0]);
        atomicAdd(&ws[OFF_RAWP + bh], rp[0]);
        atomicAdd(&ws[OFF_RAWN + bh], rn[0]);
    }
}

// ---- out = attn + gp*rf - gn*low_rf; per-block redundant top-k (jax top_k
//      semantics: value desc, tie -> lower index, strictly-positive only).
//      attn re-read here is LLC-warm (read by k_scores just before). ----
__global__ __launch_bounds__(256) void k_out(const float* __restrict__ attn,
        const float* __restrict__ ws, float* __restrict__ out) {
    unsigned int t = threadIdx.x;
    unsigned int flat = blockIdx.x * 2048 + t * 8;    // 8192 blocks x 2048 elems
    unsigned int bh = flat >> 15;                     // uniform per block
    unsigned int b  = bh >> 5;
    unsigned int h  = bh & 31;

    __shared__ float ssp[NH], snv[NH];
    __shared__ int smp[NH];
    __shared__ float s_gp, s_gn;
    if (t < NH) {
        float S0 = ws[OFF_RAWS + b * NH + t];
        ssp[t] = ws[OFF_RAWP + b * NH + t] / S0;
        snv[t] = ws[OFF_RAWN + b * NH + t] / S0;
    }
    __syncthreads();
    if (t < NH) {
        float sp = ssp[t];
        int cnt = 0;
        for (int j = 0; j < NH; ++j) { float o = ssp[j]; cnt += (o > sp) || (o == sp && j < (int)t); }
        smp[t] = (cnt < KHEADS) && (sp > 0.f);
    }
    __syncthreads();
    if (t < NH && smp[t]) snv[t] = -INFINITY;
    __syncthreads();
    if (t == 0) {
        float gp = 0.f, gn = 0.f;
        if (smp[h]) gp = GAMMA;
        else {
            float nv = snv[h];
            int cnt = 0;
            for (int j = 0; j < NH; ++j) { float o = snv[j]; cnt += (o > nv) || (o == nv && j < (int)h); }
            if ((cnt < KHEADS) && (nv > 0.f)) gn = GAMMA;
        }
        s_gp = gp; s_gn = gn;
    }
    __syncthreads();

    float gp = s_gp, gn = s_gn;
    const float* rff = ws + OFF_RFF + ((size_t)b << 15);
    unsigned int k = flat & (KF - 1);
    #pragma unroll
    for (int half8 = 0; half8 < 2; ++half8) {
        unsigned int f2 = flat + half8 * 4, k2 = k + half8 * 4;
        float4 xs = *(const float4*)(attn + f2);
        float4 rv = *(const float4*)(rff + k2);
        float va[4] = {rv.x, rv.y, rv.z, rv.w};
        float xa[4] = {xs.x, xs.y, xs.z, xs.w};
        float oa[4];
        #pragma unroll
        for (int j = 0; j < 4; ++j) {
            bool on = va[j] >= 0.f;
            float rfv  = fmaxf(va[j], 0.f);
            float lrfv = on ? fmaxf(1.f - va[j], 0.f) : 0.f;
            oa[j] = xa[j] + gp * rfv - gn * lrfv;
        }
        float4 o = {oa[0], oa[1], oa[2], oa[3]};
        *(float4*)(out + f2) = o;
    }
}

extern "C" void kernel_launch(void* const* d_in, const int* in_sizes, int n_in,
                              void* d_out, int out_size, void* d_ws, size_t ws_size,
                              hipStream_t stream) {
    const float* attn = (const float*)d_in[0];   // f32 [B,H,KF]
    const int*   mask = (const int*)d_in[1];     // int32 [B,KF]
    const float* fC   = (const float*)d_in[2];   // f32 [B,KI]
    const float* fA   = (const float*)d_in[3];
    const float* fD   = (const float*)d_in[4];
    const float* fB   = (const float*)d_in[5];
    float* out = (float*)d_out;                  // f32 [B,H,KF]
    float* ws = (float*)d_ws;

    k_pre    <<<256, 256, 0, stream>>>(fC, fA, fD, fB, mask, ws);
    k_scores <<<1024, 256, 0, stream>>>(attn, ws);
    k_out    <<<B_SZ * NH * KF / 2048, 256, 0, stream>>>(attn, ws, out);
}

// Round 3
// 146.814 us; speedup vs baseline: 1.3188x; 1.1509x over previous
//
#include <hip/hip_runtime.h>
#include <math.h>

#define GAMMA 0.3f
#define EPS 1e-6f
#define B_SZ 16
#define NH 32
#define KF 32768
#define KI 16384
#define KHEADS 7   // ceil(0.2 * 32)

typedef float f4v __attribute__((ext_vector_type(4)));

// ---- workspace layout (float indices) ----
constexpr int OFF_MU    = 0;                    // 64  (b*4+f)
constexpr int OFF_SD    = 64;                   // 64
constexpr int OFF_RAWS  = 128;                  // 512  raw softmax denom per (b,h)
constexpr int OFF_RAWP  = 640;                  // 512  raw pos numerator
constexpr int OFF_RAWN  = 1152;                 // 512  raw neg numerator
constexpr int IOFF_BSUM = 1664;                 // 256 ints (per-2048-chunk mask counts)
constexpr int OFF_RFF   = 4096;                 // B*KF  rf expanded: rf>=0 on-mask, -1 off-mask

// LESSONS (journal):
//  prev-R6: cooperative grid.sync() fusion = ~120 µs barrier cost. NO.
//  R1: hand-rolled per-batch arrive barrier + launch_bounds(256,4) regressed
//      (VGPR cap 64 -> attn re-loaded; barrier serialized tail). NO global sync.
//  R2: fusing stats into the expand kernel (redundant serial per-block stats)
//      = 47.8 µs, 9% occupancy, latency-bound. Stats must stay PARALLEL
//      (one block per (b,f)), expand separate. 4-dispatch skeleton is right.
//  Overhead model: ~82 µs harness fills + kernels + gaps. Only lever left:
//      serial-latency inside small kernels (barrier trees, dependent loads).

// ---- blocks [0,64): per-(b,feat) mean/(std+eps) via wave-shuffle reduce;
//      blocks [64,320): 2048-int mask chunk counts (first 6 also zero accums) ----
__global__ __launch_bounds__(256) void k_stats_cnt(const float* __restrict__ fC,
        const float* __restrict__ fA, const float* __restrict__ fD,
        const float* __restrict__ fB, const int* __restrict__ mask,
        float* __restrict__ ws) {
    int bid = blockIdx.x, t = threadIdx.x;
    int lane = t & 63, wid = t >> 6;
    if (bid < 64) {
        int b = bid >> 2, f = bid & 3;
        const float* src;
        if (f == 0) src = fC; else if (f == 1) src = fA; else if (f == 2) src = fD; else src = fB;
        src += (size_t)b * KI;
        double s = 0.0, s2 = 0.0;
        #pragma unroll 4
        for (int i = t; i < KI / 4; i += 256) {
            float4 v = ((const float4*)src)[i];
            s  += (double)v.x + (double)v.y + (double)v.z + (double)v.w;
            s2 += (double)v.x * v.x + (double)v.y * v.y + (double)v.z * v.z + (double)v.w * v.w;
        }
        #pragma unroll
        for (int off = 32; off > 0; off >>= 1) {
            s  += __shfl_down(s, off);
            s2 += __shfl_down(s2, off);
        }
        __shared__ double w1[4], w2[4];
        if (lane == 0) { w1[wid] = s; w2[wid] = s2; }
        __syncthreads();
        if (t == 0) {
            double S1 = w1[0] + w1[1] + w1[2] + w1[3];
            double S2 = w2[0] + w2[1] + w2[2] + w2[3];
            double mu  = S1 * (1.0 / KI);
            double var = fmax(S2 * (1.0 / KI) - mu * mu, 0.0);
            ws[OFF_MU + bid] = (float)mu;
            ws[OFF_SD + bid] = (float)(sqrt(var) + (double)EPS);
        }
    } else {
        int cblk = bid - 64;                     // 0..255, 2048 ints each
        if (cblk < 6) ws[OFF_RAWS + cblk * 256 + t] = 0.f;   // zero 1536 accum floats
        const int* mrow = mask + (size_t)cblk * 2048;
        int4 m0 = *(const int4*)(mrow + t * 8);
        int4 m1 = *(const int4*)(mrow + t * 8 + 4);
        int cnt = (m0.x != 0) + (m0.y != 0) + (m0.z != 0) + (m0.w != 0)
                + (m1.x != 0) + (m1.y != 0) + (m1.z != 0) + (m1.w != 0);
        #pragma unroll
        for (int off = 32; off > 0; off >>= 1) cnt += __shfl_down(cnt, off);
        __shared__ int wc[4];
        if (lane == 0) wc[wid] = cnt;
        __syncthreads();
        if (t == 0) ((int*)ws)[IOFF_BSUM + cblk] = wc[0] + wc[1] + wc[2] + wc[3];
    }
}

// ---- fused rf-compute + expand-to-full-K (rf on-mask, -1 off-mask).
//      Image-token ranks of block (b,c) form the contiguous feat range
//      [boff, boff+total); wave-shuffle scan for local ranks. ----
__global__ __launch_bounds__(256) void k_rf_expand(const float* __restrict__ fC,
        const float* __restrict__ fA, const float* __restrict__ fD,
        const float* __restrict__ fB, const int* __restrict__ mask,
        float* __restrict__ ws) {
    __shared__ int sb[16];
    __shared__ int wsum[4];
    __shared__ float rfbuf[2048];
    int blk = blockIdx.x, t = threadIdx.x;       // blk = b*16 + c
    int b = blk >> 4, c = blk & 15;
    int lane = t & 63, wid = t >> 6;

    // boff: parallel load of chunk counts [0,c), broadcast-sum from LDS
    const int* bsum = (const int*)ws + IOFF_BSUM;
    if (t < 16) sb[t] = (t < c) ? bsum[(b << 4) + t] : 0;

    const int* mrow = mask + (size_t)blk * 2048;
    int4 m0 = *(const int4*)(mrow + t * 8);
    int4 m1 = *(const int4*)(mrow + t * 8 + 4);
    int mv[8] = {m0.x, m0.y, m0.z, m0.w, m1.x, m1.y, m1.z, m1.w};
    int cnt = 0;
    #pragma unroll
    for (int j = 0; j < 8; ++j) cnt += (mv[j] != 0);

    // wave-inclusive scan of cnt
    int x = cnt;
    #pragma unroll
    for (int off = 1; off < 64; off <<= 1) {
        int v = __shfl_up(x, off);
        if (lane >= off) x += v;
    }
    if (lane == 63) wsum[wid] = x;
    __syncthreads();
    int base = 0;
    #pragma unroll
    for (int w = 0; w < 4; ++w) base += (w < wid) ? wsum[w] : 0;
    int total = wsum[0] + wsum[1] + wsum[2] + wsum[3];
    int rloc = base + x - cnt;                   // exclusive prefix = local rank
    int boff = 0;
    #pragma unroll
    for (int i = 0; i < 16; ++i) boff += sb[i];

    float mu0 = ws[OFF_MU + b * 4 + 0], sd0 = ws[OFF_SD + b * 4 + 0];
    float mu1 = ws[OFF_MU + b * 4 + 1], sd1 = ws[OFF_SD + b * 4 + 1];
    float mu2 = ws[OFF_MU + b * 4 + 2], sd2 = ws[OFF_SD + b * 4 + 2];
    float mu3 = ws[OFF_MU + b * 4 + 3], sd3 = ws[OFF_SD + b * 4 + 3];
    for (int j = t; j < total; j += 256) {
        size_t idx = (size_t)b * KI + boff + j;
        float Ct = fmaxf((fC[idx] - mu0) / sd0, 0.f);
        float At = 1.f / (1.f + __expf(-((fA[idx] - mu1) / sd1)));
        float Dt = 1.f / (1.f + __expf(-((fD[idx] - mu2) / sd2)));
        float Bt = 1.f / (1.f + __expf(-((fB[idx] - mu3) / sd3)));
        float denom = fmaxf(1.f + 0.5f * (Dt + Bt), EPS);
        rfbuf[j] = fmaxf(Ct * At / denom, 0.f);
    }
    __syncthreads();
    float vr[8];
    #pragma unroll
    for (int j = 0; j < 8; ++j) {
        if (mv[j]) { vr[j] = rfbuf[rloc]; ++rloc; }
        else       { vr[j] = -1.f; }
    }
    float* rff = ws + OFF_RFF + (size_t)blk * 2048 + t * 8;
    *(float4*)(rff)     = *(float4*)(vr);
    *(float4*)(rff + 4) = *(float4*)(vr + 4);
}

// ---- per-(b,h)-quarter raw masked-softmax accumulation (branchless, no
//      max-sub: |x|<~6 -> e^x <= ~300; raw sums combined via atomicAdd).
//      2048 blocks (8/CU) for TLP on the cold 64 MB attn read. ----
__global__ __launch_bounds__(256) void k_scores(const float* __restrict__ attn,
                                                float* __restrict__ ws) {
    int g = blockIdx.x, t = threadIdx.x;         // 2048 blocks: bh = g>>2, qtr = g&3
    int bh = g >> 2, qtr = g & 3;
    int b = bh >> 5;
    const float* xr  = attn + ((size_t)bh << 15) + ((size_t)qtr << 13);
    const float* rff = ws + OFF_RFF + ((size_t)b << 15) + ((size_t)qtr << 13);
    float S = 0.f, P = 0.f, N = 0.f;
    #pragma unroll
    for (int i = 0; i < 8; ++i) {
        int k = (i * 256 + t) * 4;
        float4 xs = *(const float4*)(xr + k);
        float4 rv = *(const float4*)(rff + k);
        float xa[4] = {xs.x, xs.y, xs.z, xs.w};
        float va[4] = {rv.x, rv.y, rv.z, rv.w};
        #pragma unroll
        for (int j = 0; j < 4; ++j) {
            float e = __expf(xa[j]);
            bool on = va[j] >= 0.f;
            float rfv  = fmaxf(va[j], 0.f);
            float lrfv = on ? fmaxf(1.f - va[j], 0.f) : 0.f;
            S += on ? e : 0.f;
            P = fmaf(e, rfv, P);
            N = fmaf(e, lrfv, N);
        }
    }
    int lane = t & 63, wid = t >> 6;
    #pragma unroll
    for (int off = 32; off > 0; off >>= 1) {
        S += __shfl_down(S, off);
        P += __shfl_down(P, off);
        N += __shfl_down(N, off);
    }
    __shared__ float wS[4], wP[4], wN[4];
    if (lane == 0) { wS[wid] = S; wP[wid] = P; wN[wid] = N; }
    __syncthreads();
    if (t == 0) {
        atomicAdd(&ws[OFF_RAWS + bh], wS[0] + wS[1] + wS[2] + wS[3]);
        atomicAdd(&ws[OFF_RAWP + bh], wP[0] + wP[1] + wP[2] + wP[3]);
        atomicAdd(&ws[OFF_RAWN + bh], wN[0] + wN[1] + wN[2] + wN[3]);
    }
}

// ---- out = attn + gp*rf - gn*low_rf; per-block redundant top-k (jax top_k
//      semantics: value desc, tie -> lower index, strictly-positive only).
//      Chunk swizzle puts each block on the XCD whose L2 read this attn
//      region in k_scores (scores block g covers 8 chunks; XCD = g%8).
//      Nontemporal out stores keep attn LLC-resident for trailing blocks. ----
__global__ __launch_bounds__(256) void k_out(const float* __restrict__ attn,
        const float* __restrict__ ws, float* __restrict__ out) {
    unsigned int t = threadIdx.x;
    unsigned int j = blockIdx.x;                 // 8192 blocks
    unsigned int r = j & 7, q = j >> 3;
    unsigned int chunk = 8u * r + 64u * (q >> 3) + (q & 7);   // bijective, XCD-matched
    unsigned int flat = chunk * 2048 + t * 8;
    unsigned int bh = flat >> 15;                // uniform per block (2048 | 32768)
    unsigned int b  = bh >> 5;
    unsigned int h  = bh & 31;

    __shared__ float ssp[NH], snv[NH];
    __shared__ int smp[NH];
    __shared__ float s_gp, s_gn;
    if (t < NH) {
        float S0 = ws[OFF_RAWS + b * NH + t];
        ssp[t] = ws[OFF_RAWP + b * NH + t] / S0;
        snv[t] = ws[OFF_RAWN + b * NH + t] / S0;
    }
    __syncthreads();
    if (t < NH) {
        float sp = ssp[t];
        int cnt = 0;
        for (int jj = 0; jj < NH; ++jj) { float o = ssp[jj]; cnt += (o > sp) || (o == sp && jj < (int)t); }
        smp[t] = (cnt < KHEADS) && (sp > 0.f);
    }
    __syncthreads();
    if (t < NH && smp[t]) snv[t] = -INFINITY;
    __syncthreads();
    if (t == 0) {
        float gp = 0.f, gn = 0.f;
        if (smp[h]) gp = GAMMA;
        else {
            float nv = snv[h];
            int cnt = 0;
            for (int jj = 0; jj < NH; ++jj) { float o = snv[jj]; cnt += (o > nv) || (o == nv && jj < (int)h); }
            if ((cnt < KHEADS) && (nv > 0.f)) gn = GAMMA;
        }
        s_gp = gp; s_gn = gn;
    }
    __syncthreads();

    float gp = s_gp, gn = s_gn;
    const float* rff = ws + OFF_RFF + ((size_t)b << 15);
    unsigned int k = flat & (KF - 1);
    #pragma unroll
    for (int half8 = 0; half8 < 2; ++half8) {
        unsigned int f2 = flat + half8 * 4, k2 = k + half8 * 4;
        float4 xs = *(const float4*)(attn + f2);
        float4 rv = *(const float4*)(rff + k2);
        float va[4] = {rv.x, rv.y, rv.z, rv.w};
        float xa[4] = {xs.x, xs.y, xs.z, xs.w};
        float oa[4];
        #pragma unroll
        for (int jj = 0; jj < 4; ++jj) {
            bool on = va[jj] >= 0.f;
            float rfv  = fmaxf(va[jj], 0.f);
            float lrfv = on ? fmaxf(1.f - va[jj], 0.f) : 0.f;
            oa[jj] = xa[jj] + gp * rfv - gn * lrfv;
        }
        f4v o = {oa[0], oa[1], oa[2], oa[3]};
        __builtin_nontemporal_store(o, (f4v*)(out + f2));
    }
}

extern "C" void kernel_launch(void* const* d_in, const int* in_sizes, int n_in,
                              void* d_out, int out_size, void* d_ws, size_t ws_size,
                              hipStream_t stream) {
    const float* attn = (const float*)d_in[0];   // f32 [B,H,KF]
    const int*   mask = (const int*)d_in[1];     // int32 [B,KF]
    const float* fC   = (const float*)d_in[2];   // f32 [B,KI]
    const float* fA   = (const float*)d_in[3];
    const float* fD   = (const float*)d_in[4];
    const float* fB   = (const float*)d_in[5];
    float* out = (float*)d_out;                  // f32 [B,H,KF]
    float* ws = (float*)d_ws;

    k_stats_cnt<<<320, 256, 0, stream>>>(fC, fA, fD, fB, mask, ws);
    k_rf_expand<<<256, 256, 0, stream>>>(fC, fA, fD, fB, mask, ws);
    k_scores   <<<2048, 256, 0, stream>>>(attn, ws);
    k_out      <<<B_SZ * NH * KF / 2048, 256, 0, stream>>>(attn, ws, out);
}